// Round 1
// baseline (6010.568 us; speedup 1.0000x reference)
//
#include <hip/hip_runtime.h>

#define HID 256
#define HH  64
#define WW  64
#define KH  (HID/2)   // 128 packed half2 per 256-vector

typedef _Float16 h2_t __attribute__((ext_vector_type(2)));

union UH2 { unsigned int u; h2_t h; _Float16 e[2]; };

__device__ __forceinline__ float dot2acc(unsigned int w2, unsigned int hv, float acc) {
#if defined(__has_builtin) && __has_builtin(__builtin_amdgcn_fdot2)
    UH2 a, b; a.u = w2; b.u = hv;
    return __builtin_amdgcn_fdot2(a.h, b.h, acc, false);
#else
    UH2 a, b; a.u = w2; b.u = hv;
    acc = fmaf((float)a.e[0], (float)b.e[0], acc);
    acc = fmaf((float)a.e[1], (float)b.e[1], acc);
    return acc;
#endif
}

__global__ __launch_bounds__(256, 1)
void mrf_scan_kernel(const float* __restrict__ x,
                     const float* __restrict__ w_xh,
                     const float* __restrict__ b_xh,
                     const float* __restrict__ w_hh,
                     const float* __restrict__ b_hh,
                     float* __restrict__ out)
{
    const int n = blockIdx.x;
    const int o = threadIdx.x;

    // h of previous column step (current row), packed f16
    __shared__ unsigned int hprev[KH];
    // h of row below, per column, packed f16 (overwritten in place as the
    // current row is produced — each column is consumed before overwrite)
    __shared__ unsigned int hbel[WW][KH];

    // ---- zero-init LDS (edge steps multiply dots by 0; 0*0 stays clean) ----
    {
        unsigned int* z = &hbel[0][0];
        #pragma unroll
        for (int q = 0; q < (WW*KH)/256; ++q) z[o + 256*q] = 0u;
        if (o < KH) hprev[o] = 0u;
    }

    // ---- preload this thread's w_hh row as 128 packed f16 pairs ----
    unsigned int wreg[KH];
    {
        const float* wr = w_hh + (size_t)o * HID;
        #pragma unroll
        for (int q = 0; q < KH; ++q) {
            UH2 u;
            u.e[0] = (_Float16)wr[2*q+0];
            u.e[1] = (_Float16)wr[2*q+1];
            wreg[q] = u.u;
        }
    }

    const float wx0 = w_xh[o*3+0];
    const float wx1 = w_xh[o*3+1];
    const float wx2 = w_xh[o*3+2];
    const float bx  = b_xh[o];
    const float bh  = b_hh[o];

    const int   XP  = HH*WW;
    const float* xn = x + (size_t)n * 3 * XP;
    float* outn = out + ((size_t)n * HID + o) * (size_t)XP;

    __syncthreads();   // LDS init visible

    for (int k = 0; k < HH; ++k) {
        const int  i    = HH - 1 - k;
        const int  flip = ((i & 1) == 0);          // even rows scan right->left
        const float fB  = (k > 0) ? 1.f : 0.f;     // below-row contribution active?
        for (int t = 0; t < WW; ++t) {
            const int   w  = flip ? (WW-1-t) : t;
            const float fS = (t > 0) ? 1.f : 0.f;  // in-row scan contribution active?

            // ---- logit term, derived on the fly (uniform x loads) ----
            float s0=0.f, s1=0.f, s2=0.f, cnt=0.f;
            if (w > 0)    { const int p = i*WW + (w-1); s0+=xn[p]; s1+=xn[XP+p]; s2+=xn[2*XP+p]; cnt+=1.f; }
            if (w < WW-1) { const int p = i*WW + (w+1); s0+=xn[p]; s1+=xn[XP+p]; s2+=xn[2*XP+p]; cnt+=1.f; }
            if (i > 0)    { const int p = (i-1)*WW + w; s0+=xn[p]; s1+=xn[XP+p]; s2+=xn[2*XP+p]; cnt+=1.f; }
            if (i < HH-1) { const int p = (i+1)*WW + w; s0+=xn[p]; s1+=xn[XP+p]; s2+=xn[2*XP+p]; cnt+=1.f; }

            float acc = cnt * bx;
            acc = fmaf(s0, wx0, acc);
            acc = fmaf(s1, wx1, acc);
            acc = fmaf(s2, wx2, acc);
            const float hpat = (((w != 0) && (w != WW-1)) ? 1.f : 0.f)
                             + ((i != 0) ? 1.f : 0.f);
            acc = fmaf(hpat, bh, acc);

            // ---- the two 256-dots: below-row h and previous-column h ----
            float aB0=0.f, aB1=0.f, aB2=0.f, aB3=0.f;
            float aS0=0.f, aS1=0.f, aS2=0.f, aS3=0.f;
            const uint4* hb4 = (const uint4*)(&hbel[w][0]);
            const uint4* hp4 = (const uint4*)(&hprev[0]);
            #pragma unroll
            for (int q = 0; q < KH/4; ++q) {
                const uint4 hv = hb4[q];
                const uint4 pv = hp4[q];
                aB0 = dot2acc(wreg[4*q+0], hv.x, aB0);
                aB1 = dot2acc(wreg[4*q+1], hv.y, aB1);
                aB2 = dot2acc(wreg[4*q+2], hv.z, aB2);
                aB3 = dot2acc(wreg[4*q+3], hv.w, aB3);
                aS0 = dot2acc(wreg[4*q+0], pv.x, aS0);
                aS1 = dot2acc(wreg[4*q+1], pv.y, aS1);
                aS2 = dot2acc(wreg[4*q+2], pv.z, aS2);
                aS3 = dot2acc(wreg[4*q+3], pv.w, aS3);
            }
            acc += fB * (((aB0+aB1) + (aB2+aB3)) + bh);
            acc += fS * (((aS0+aS1) + (aS2+aS3)) + bh);

            const float e    = __expf(-acc);
            const float hnew = 1.0f / (1.0f + e);

            outn[i*WW + w] = hnew;               // f32 output, full precision

            __syncthreads();                     // all reads of hprev/hbel[w] done
            const _Float16 h16 = (_Float16)hnew;
            ((_Float16*)hprev)[o]        = h16;
            ((_Float16*)&hbel[w][0])[o]  = h16;
            __syncthreads();                     // writes visible to next step
        }
    }
}

extern "C" void kernel_launch(void* const* d_in, const int* in_sizes, int n_in,
                              void* d_out, int out_size, void* d_ws, size_t ws_size,
                              hipStream_t stream) {
    const float* x    = (const float*)d_in[0];
    const float* w_xh = (const float*)d_in[1];
    const float* b_xh = (const float*)d_in[2];
    const float* w_hh = (const float*)d_in[3];
    const float* b_hh = (const float*)d_in[4];
    float* out = (float*)d_out;
    (void)in_sizes; (void)n_in; (void)d_ws; (void)ws_size; (void)out_size;

    mrf_scan_kernel<<<dim3(32), dim3(256), 0, stream>>>(x, w_xh, b_xh, w_hh, b_hh, out);
}

// Round 2
// 2932.276 us; speedup vs baseline: 2.0498x; 2.0498x over previous
//
#include <hip/hip_runtime.h>

#define HID 256
#define HH  64
#define WW  64

typedef _Float16 f16x8 __attribute__((ext_vector_type(8)));
typedef float    f32x4 __attribute__((ext_vector_type(4)));

__global__ __launch_bounds__(256, 1)
void mrf_scan_kernel(const float* __restrict__ x,
                     const float* __restrict__ w_xh,
                     const float* __restrict__ b_xh,
                     const float* __restrict__ w_hh,
                     const float* __restrict__ b_hh,
                     float* __restrict__ out)
{
    const int n   = blockIdx.x;
    const int tid = threadIdx.x;
    const int wv  = tid >> 6;    // wave 0..3
    const int l   = tid & 63;
    const int l15 = l & 15;
    const int lq  = l >> 4;
    const int nbase = wv * 64;   // this wave's output-channel base

    __shared__ __align__(16) float    pre[WW][HID + 4];   // +4 pad: spread quarter-rows across banks
    __shared__ __align__(16) _Float16 hbel[WW][HID];      // XOR-swizzled storage
    __shared__ __align__(16) _Float16 hp[2][HID];         // ping-pong h_prev
    __shared__ __align__(16) float    xs[4][WW];          // neighbor sums + count

    // ---- preload w_hh as MFMA B-fragments: B[k=g][col=o], o = nbase+nt*16+l15 ----
    f16x8 Bf[4][8];
    #pragma unroll
    for (int nt = 0; nt < 4; ++nt) {
        const float* wr = w_hh + (size_t)(nbase + nt*16 + l15) * HID;
        #pragma unroll
        for (int kf = 0; kf < 8; ++kf) {
            const int g0 = kf*32 + lq*8;
            f16x8 b;
            #pragma unroll
            for (int j = 0; j < 8; ++j) b[j] = (_Float16)wr[g0 + j];
            Bf[nt][kf] = b;
        }
    }

    // per-own-channel constants (o = tid) for the logit precompute
    const float wx0 = w_xh[tid*3+0];
    const float wx1 = w_xh[tid*3+1];
    const float wx2 = w_xh[tid*3+2];
    const float bx  = b_xh[tid];
    const float bh  = b_hh[tid];

    float bhv[4];
    #pragma unroll
    for (int nt = 0; nt < 4; ++nt) bhv[nt] = b_hh[nbase + nt*16 + l15];

    const int    XP = HH*WW;
    const float* xn = x + (size_t)n * 3 * XP;
    float*     outn = out + (size_t)n * HID * XP;

    int cur = 0;
    for (int k = 0; k < HH; ++k) {
        const int i    = HH - 1 - k;
        const int flip = ((i & 1) == 0);   // even rows scan right->left

        // stage x neighbor-sums for this row (wave 0), zero h_prev buffer
        if (tid < WW) {
            const int w = tid;
            float s0=0.f, s1=0.f, s2=0.f, c=0.f;
            if (w > 0)    { int p = i*WW + (w-1); s0+=xn[p]; s1+=xn[XP+p]; s2+=xn[2*XP+p]; c+=1.f; }
            if (w < WW-1) { int p = i*WW + (w+1); s0+=xn[p]; s1+=xn[XP+p]; s2+=xn[2*XP+p]; c+=1.f; }
            if (i > 0)    { int p = (i-1)*WW + w; s0+=xn[p]; s1+=xn[XP+p]; s2+=xn[2*XP+p]; c+=1.f; }
            if (i < HH-1) { int p = (i+1)*WW + w; s0+=xn[p]; s1+=xn[XP+p]; s2+=xn[2*XP+p]; c+=1.f; }
            xs[0][w]=s0; xs[1][w]=s1; xs[2][w]=s2; xs[3][w]=c;
        }
        if (tid < 128) ((unsigned int*)(&hp[cur][0]))[tid] = 0u;  // scan starts from h=0
        __syncthreads();

        // column-independent logit into pre[w][o]  (o = tid)
        {
            const float bh_fix = ((i != 0) ? bh : 0.f) + ((k > 0) ? bh : 0.f);
            #pragma unroll 4
            for (int w = 0; w < WW; ++w) {
                float lx = xs[3][w]*bx + bh_fix;
                if (w != 0 && w != WW-1) lx += bh;   // h0 left/right prior term
                lx = fmaf(xs[0][w], wx0, lx);
                lx = fmaf(xs[1][w], wx1, lx);
                lx = fmaf(xs[2][w], wx2, lx);
                pre[w][tid] = lx;
            }
        }
        __syncthreads();

        // below-row recurrence term via MFMA: pre[w][o] += sum_g hbel[w][g]*w_hh[o][g]
        if (k > 0) {
            #pragma unroll
            for (int mt = 0; mt < 4; ++mt) {
                const int wrow = mt*16 + l15;       // A row = l&15
                f16x8 Af[8];
                #pragma unroll
                for (int kf = 0; kf < 8; ++kf) {
                    const int byt = (wrow*512 + kf*64 + lq*16) ^ ((wrow & 7) << 4);
                    Af[kf] = *(const f16x8*)((const char*)(&hbel[0][0]) + byt);
                }
                f32x4 c[4];
                #pragma unroll
                for (int nt = 0; nt < 4; ++nt)
                    #pragma unroll
                    for (int r = 0; r < 4; ++r)
                        c[nt][r] = pre[mt*16 + lq*4 + r][nbase + nt*16 + l15];
                #pragma unroll
                for (int nt = 0; nt < 4; ++nt)
                    #pragma unroll
                    for (int kf = 0; kf < 8; ++kf)
                        c[nt] = __builtin_amdgcn_mfma_f32_16x16x32_f16(Af[kf], Bf[nt][kf], c[nt], 0, 0, 0);
                #pragma unroll
                for (int nt = 0; nt < 4; ++nt)
                    #pragma unroll
                    for (int r = 0; r < 4; ++r)
                        pre[mt*16 + lq*4 + r][nbase + nt*16 + l15] = c[nt][r];
            }
        }
        __syncthreads();

        // ---- serial column scan: h = sigmoid(pre[w] + W*h_prev (+bh if t>0)) ----
        for (int t = 0; t < WW; ++t) {
            const int w = flip ? (WW-1-t) : t;

            f16x8 Af[8];   // replicated A rows: every lane reads h_prev k-slice for its quarter
            #pragma unroll
            for (int kf = 0; kf < 8; ++kf)
                Af[kf] = *(const f16x8*)((const char*)(&hp[cur][0]) + kf*64 + lq*16);

            f32x4 c[4];
            #pragma unroll
            for (int nt = 0; nt < 4; ++nt) {
                c[nt][0] = pre[w][nbase + nt*16 + l15];   // D row0 init = pre
                c[nt][1] = 0.f; c[nt][2] = 0.f; c[nt][3] = 0.f;
            }
            #pragma unroll
            for (int nt = 0; nt < 4; ++nt)
                #pragma unroll
                for (int kf = 0; kf < 8; ++kf)
                    c[nt] = __builtin_amdgcn_mfma_f32_16x16x32_f16(Af[kf], Bf[nt][kf], c[nt], 0, 0, 0);

            if (l < 16) {   // D row 0 lives in lanes 0-15, reg 0
                #pragma unroll
                for (int nt = 0; nt < 4; ++nt) {
                    const int o = nbase + nt*16 + l15;
                    const float val = c[nt][0] + ((t > 0) ? bhv[nt] : 0.f);
                    const float s = 1.f / (1.f + __expf(-val));
                    outn[(size_t)o*XP + i*WW + w] = s;
                    const _Float16 h16 = (_Float16)s;
                    hp[cur ^ 1][o] = h16;
                    *(_Float16*)((char*)(&hbel[0][0]) + ((w*512 + o*2) ^ ((w & 7) << 4))) = h16;
                }
            }
            __syncthreads();
            cur ^= 1;
        }
    }
}

extern "C" void kernel_launch(void* const* d_in, const int* in_sizes, int n_in,
                              void* d_out, int out_size, void* d_ws, size_t ws_size,
                              hipStream_t stream) {
    const float* x    = (const float*)d_in[0];
    const float* w_xh = (const float*)d_in[1];
    const float* b_xh = (const float*)d_in[2];
    const float* w_hh = (const float*)d_in[3];
    const float* b_hh = (const float*)d_in[4];
    float* out = (float*)d_out;
    (void)in_sizes; (void)n_in; (void)d_ws; (void)ws_size; (void)out_size;

    mrf_scan_kernel<<<dim3(32), dim3(256), 0, stream>>>(x, w_xh, b_xh, w_hh, b_hh, out);
}

// Round 3
// 1919.092 us; speedup vs baseline: 3.1320x; 1.5279x over previous
//
#include <hip/hip_runtime.h>

#define HID 256
#define HH  64
#define WW  64

typedef _Float16 f16x8 __attribute__((ext_vector_type(8)));
typedef float    f32x4 __attribute__((ext_vector_type(4)));

__global__ __launch_bounds__(256, 1)
void mrf_scan_kernel(const float* __restrict__ x,
                     const float* __restrict__ w_xh,
                     const float* __restrict__ b_xh,
                     const float* __restrict__ w_hh,
                     const float* __restrict__ b_hh,
                     float* __restrict__ out)
{
    const int n   = blockIdx.x;
    const int tid = threadIdx.x;
    const int wv  = tid >> 6;    // wave 0..3
    const int l   = tid & 63;
    const int l15 = l & 15;
    const int lq  = l >> 4;
    const int nbase = wv * 64;
    const int o   = nbase + l;   // this lane's output channel (= nbase + lq*16 + l15)

    // hbel[w][o]: h of the row below, per column (linear layout — only per-lane
    // contiguous u16 accesses remain, conflict-free). Overwritten in place as
    // the current row is produced; each column read (w_{t+1}) before its write (w_t).
    __shared__ __align__(16) _Float16 hbel[WW][HID];
    // hsum[cur][g] = h_prev[g] + hbel[w_next][g], ping-pong (written at step t,
    // read as MFMA A-fragments at step t+1 after the barrier)
    __shared__ __align__(16) _Float16 hsum[2][HID];
    // per-row x neighbor sums: xs4[w] = (s_c0, s_c1, s_c2, cnt)
    __shared__ __align__(16) float4   xs4[WW];

    // ---- zero-init LDS (hbel=0 => bottom row has no below-term; hsum=0 => t=0 of row 0) ----
    {
        unsigned int* z = (unsigned int*)(&hbel[0][0]);
        #pragma unroll
        for (int q = 0; q < (WW*HID/2)/256; ++q) z[tid + 256*q] = 0u;
        ((unsigned int*)(&hsum[0][0]))[tid] = 0u;   // 2*256 f16 = 256 dwords
    }

    // ---- preload w_hh as MFMA B-fragments: B[k=g][col], col -> channel nbase+nt*16+l15 ----
    f16x8 Bf[4][8];
    #pragma unroll
    for (int nt = 0; nt < 4; ++nt) {
        const float* wr = w_hh + (size_t)(nbase + nt*16 + l15) * HID;
        #pragma unroll
        for (int kf = 0; kf < 8; ++kf) {
            const int g0 = kf*32 + lq*8;
            f16x8 b;
            #pragma unroll
            for (int j = 0; j < 8; ++j) b[j] = (_Float16)wr[g0 + j];
            Bf[nt][kf] = b;
        }
    }

    // per-lane channel constants
    const float wx0 = w_xh[o*3+0];
    const float wx1 = w_xh[o*3+1];
    const float wx2 = w_xh[o*3+2];
    const float bx  = b_xh[o];
    const float bh  = b_hh[o];

    const int    XP = HH*WW;
    const float* xn = x + (size_t)n * 3 * XP;
    float*     outn = out + (size_t)n * HID * XP;

    __syncthreads();

    int cur = 0;
    for (int k = 0; k < HH; ++k) {
        const int i    = HH - 1 - k;
        const int flip = ((i & 1) == 0);   // even rows scan right->left

        // ---- stage x neighbor sums for this row (waves 0..2; c = wave) ----
        if (tid < 192) {
            const int c = tid >> 6, w = tid & 63;
            const float* xc = xn + (size_t)c * XP;
            float s = 0.f;
            if (w > 0)    s += xc[i*WW + w - 1];
            if (w < WW-1) s += xc[i*WW + w + 1];
            if (i > 0)    s += xc[(i-1)*WW + w];
            if (i < HH-1) s += xc[(i+1)*WW + w];
            ((float*)&xs4[w])[c] = s;
            if (c == 0) {
                const float cnt = (float)((w>0) + (w<WW-1) + (i>0) + (i<HH-1));
                ((float*)&xs4[w])[3] = cnt;
            }
        }
        __syncthreads();

        const float Fr = ((i != 0) ? 1.f : 0.f) + ((k != 0) ? 1.f : 0.f);
        float* outrow = outn + (size_t)i * WW;

        for (int t = 0; t < WW; ++t) {
            const int w = flip ? (WW-1-t) : t;

            // A-fragments: replicated rows of (h_prev + h_below[w]) from hsum[cur]
            f16x8 Af[8];
            #pragma unroll
            for (int kf = 0; kf < 8; ++kf)
                Af[kf] = *(const f16x8*)((const char*)(&hsum[cur][0]) + kf*64 + lq*16);

            // per-lane x-logit (overlaps with LDS read latency; off MFMA critical path)
            const float4 xv = xs4[w];
            const float Ft = Fr + ((t != 0 && t != WW-1) ? 1.f : 0.f) + ((t != 0) ? 1.f : 0.f);
            float pre = xv.w * bx;
            pre = fmaf(xv.x, wx0, pre);
            pre = fmaf(xv.y, wx1, pre);
            pre = fmaf(xv.z, wx2, pre);
            pre = fmaf(Ft,   bh,  pre);

            f32x4 c[4];
            #pragma unroll
            for (int nt = 0; nt < 4; ++nt) c[nt] = (f32x4){0.f, 0.f, 0.f, 0.f};
            #pragma unroll
            for (int nt = 0; nt < 4; ++nt)
                #pragma unroll
                for (int kf = 0; kf < 8; ++kf)
                    c[nt] = __builtin_amdgcn_mfma_f32_16x16x32_f16(Af[kf], Bf[nt][kf], c[nt], 0, 0, 0);

            // C=0 and replicated A rows => all D rows equal; lane picks its nt=lq
            const float dot = (lq < 2) ? ((lq == 0) ? c[0][0] : c[1][0])
                                       : ((lq == 2) ? c[2][0] : c[3][0]);
            const float val = dot + pre;
            const float e   = __expf(-val);
            const float s   = __builtin_amdgcn_rcpf(1.f + e);

            outrow[(size_t)o * XP + w] = s;

            // next-step A value: h16 + below(next column); at t=63 the next step is
            // the row above at the same column: below = h16 itself, h_prev = 0.
            const int wn = (t < WW-1) ? (flip ? (WW-2-t) : (t+1)) : w;
            const _Float16 hb  = hbel[wn][o];      // read before hbel[w] write; wn != w for t<63
            const _Float16 h16 = (_Float16)s;
            hbel[w][o] = h16;
            hsum[cur ^ 1][o] = (t < WW-1) ? (_Float16)(h16 + hb) : h16;

            __syncthreads();
            cur ^= 1;
        }
    }
}

extern "C" void kernel_launch(void* const* d_in, const int* in_sizes, int n_in,
                              void* d_out, int out_size, void* d_ws, size_t ws_size,
                              hipStream_t stream) {
    const float* x    = (const float*)d_in[0];
    const float* w_xh = (const float*)d_in[1];
    const float* b_xh = (const float*)d_in[2];
    const float* w_hh = (const float*)d_in[3];
    const float* b_hh = (const float*)d_in[4];
    float* out = (float*)d_out;
    (void)in_sizes; (void)n_in; (void)d_ws; (void)ws_size; (void)out_size;

    mrf_scan_kernel<<<dim3(32), dim3(256), 0, stream>>>(x, w_xh, b_xh, w_hh, b_hh, out);
}